// Round 8
// baseline (346.330 us; speedup 1.0000x reference)
//
#include <hip/hip_runtime.h>
#include <math.h>

#define BB 8
#define CC 256
#define KK 19
#define HW 16384
#define HW4 4096            // HW / 4 (float4 units)

#define CHUNK4 32           // float4 per hw-chunk = 128 floats
#define NS (HW4 / CHUNK4)   // 128 chunks per batch

// ---- K1 history ----
// r1: thread-per-channel, map in LDS: 93 us. 608 broadcast ds_reads/wave +
//     marginal spill at VGPR=64.
// r2/r3: more ch/thread -> compiler pinned 64 VGPRs -> acc in scratch ->
//     GBs of scratch traffic. Lesson: design INSIDE 64 VGPRs.
// r4/r5: map->SGPR via asm s_load: works but per-j lgkmcnt(0) full drain
//     -> 100 us.
// r6: constant-AS map pointers -> compiler-scheduled s_load_dwordx4,
//     K1 ~60-79 us.
// r7: 2D wave split halved DS reads AND bank conflicts -> NO change (82 us).
//     DS was never critical. True bottleneck: block-wide vmcnt(0) barrier
//     phases with only ~2.75 blocks/CU resident -> all pipes idle.
// r8 (this): delete LDS/barriers/staging entirely. Thread t = channel c;
//     map via SGPR s_loads (r6 path, wave-shared); feature streamed
//     per-lane in f[8] batches = exactly one 128B line, fully consumed
//     back-to-back (no re-fetch; L2 absorbs stragglers). Zero sync ->
//     latency hidden by pure TLP. VGPR: acc19+f8(32)+addr ~ 58 < 64;
//     map costs SGPRs only, so r1's spill margin is restored.

typedef float f32x4 __attribute__((ext_vector_type(4)));

// Constant-AS vector pointer: uniform address + read-only memory -> s_load.
typedef const __attribute__((address_space(4))) f32x4* cvec4p;
#define CVEC4(p) ((cvec4p)(unsigned long long)(p))

// Macro-unrolled k loops: guarantees literal indices -> SROA -> registers.
#define FOR_K(OP) OP(0) OP(1) OP(2) OP(3) OP(4) OP(5) OP(6) OP(7) OP(8) OP(9) \
                  OP(10) OP(11) OP(12) OP(13) OP(14) OP(15) OP(16) OP(17) OP(18)

__global__ __launch_bounds__(256) void CGM_k1_contract(
    const float* __restrict__ feature,
    const float* __restrict__ map_,
    float* __restrict__ att,        // fallback target (pre-zeroed)
    float* __restrict__ part)       // [KK][BB][NS][CC] partials, or nullptr
{
    const int bI = blockIdx.x;      // b*NS + s
    const int s  = bI & (NS - 1);
    const int b  = bI >> 7;         // NS == 128
    const int c  = threadIdx.x;     // this thread's channel

    // Map row pointers: derived from blockIdx only -> wave-uniform by
    // construction -> backend selects s_load_dwordx4, compiler-scheduled
    // (batched, counted waits, prefetched across the unrolled j loop).
    const float* mw = map_ + (size_t)b * KK * HW + (size_t)s * (CHUNK4 * 4);
#define DECLM(K) cvec4p cm##K = CVEC4(mw + (size_t)(K) * HW);
    FOR_K(DECLM)
#undef DECLM

    float acc[KK];
#define ZERO(K) acc[K] = 0.f;
    FOR_K(ZERO)
#undef ZERO

    // This thread's feature row segment: 32 float4 = 4 full 128B lines.
    const float4* fb = (const float4*)feature
                     + ((size_t)b * CC + c) * HW4 + s * CHUNK4;

    // Per group: load one full 128B line (8 float4) back-to-back, consume
    // it hot. Per j: 19 SGPR map rows feed 76 FMAs; no LDS, no barriers.
#pragma unroll 1
    for (int g = 0; g < 4; ++g) {
        float4 f[8];
#pragma unroll
        for (int u = 0; u < 8; ++u) f[u] = fb[g * 8 + u];
#pragma unroll
        for (int u = 0; u < 8; ++u) {
            const int jj = g * 8 + u;
            const float4 fv = f[u];
#define STEP(K) { const f32x4 m = cm##K[jj]; \
                  acc[K] += fv.x * m.x + fv.y * m.y + fv.z * m.z + fv.w * m.w; }
            FOR_K(STEP)
#undef STEP
        }
    }

    if (part) {
        // part[k][b][s][c]: per k one coalesced 1KB block store (c = t).
#define FIN(K) { part[((size_t)((K) * BB + b) * NS + s) * CC + c] = acc[K]; }
        FOR_K(FIN)
#undef FIN
    } else {
        // Fallback: fp32 atomics into pre-zeroed att.
#define FIN(K) atomicAdd(&att[(size_t)(b * CC + c) * KK + (K)], acc[K]);
        FOR_K(FIN)
#undef FIN
    }
}

// ---- K1b: fold the NS=128 hw-chunk partials into att (validated r1-r7). ----
__global__ __launch_bounds__(256) void CGM_k1b_reduce(
    const float* __restrict__ part,
    float* __restrict__ att)
{
    const int bk = blockIdx.x;      // b*KK + k
    const int b  = bk / KK;
    const int k  = bk - b * KK;
    const int t  = threadIdx.x;
    const int q  = t & 63;          // float4 column: channels 4q..4q+3
    const int sg = t >> 6;          // s quarter: 32 rows

    const float4* p4 = (const float4*)(part + (size_t)(k * BB + b) * NS * CC)
                     + (size_t)(sg * 32) * 64 + q;

    float4 a0 = {0.f, 0.f, 0.f, 0.f}, a1 = a0, a2 = a0, a3 = a0;
#pragma unroll 2
    for (int i = 0; i < 32; i += 4) {
        const float4 v0 = p4[(size_t)(i + 0) * 64];
        const float4 v1 = p4[(size_t)(i + 1) * 64];
        const float4 v2 = p4[(size_t)(i + 2) * 64];
        const float4 v3 = p4[(size_t)(i + 3) * 64];
        a0.x += v0.x; a0.y += v0.y; a0.z += v0.z; a0.w += v0.w;
        a1.x += v1.x; a1.y += v1.y; a1.z += v1.z; a1.w += v1.w;
        a2.x += v2.x; a2.y += v2.y; a2.z += v2.z; a2.w += v2.w;
        a3.x += v3.x; a3.y += v3.y; a3.z += v3.z; a3.w += v3.w;
    }
    float4 r;
    r.x = (a0.x + a1.x) + (a2.x + a3.x);
    r.y = (a0.y + a1.y) + (a2.y + a3.y);
    r.z = (a0.z + a1.z) + (a2.z + a3.z);
    r.w = (a0.w + a1.w) + (a2.w + a3.w);

    __shared__ float4 red[4][64];
    red[sg][q] = r;
    __syncthreads();
    if (t < 64) {
        const float4 u0 = red[0][q], u1 = red[1][q], u2 = red[2][q], u3 = red[3][q];
        float4 o;
        o.x = (u0.x + u1.x) + (u2.x + u3.x);
        o.y = (u0.y + u1.y) + (u2.y + u3.y);
        o.z = (u0.z + u1.z) + (u2.z + u3.z);
        o.w = (u0.w + u1.w) + (u2.w + u3.w);
        float* d = att + ((size_t)b * CC + 4 * q) * KK + k;
        d[0 * KK] = o.x;
        d[1 * KK] = o.y;
        d[2 * KK] = o.z;
        d[3 * KK] = o.w;
    }
}

// ---- K2: gate + apply (frozen since round 2) ----
#define S2 8                 // hw splits
#define CT2 16               // channels per block
#define CHUNK24 (HW4 / S2)   // 512 float4

__global__ __launch_bounds__(256) void CGM_k2_apply(
    const float* __restrict__ feature,
    const float* __restrict__ gamma,
    const float* __restrict__ att,
    float* __restrict__ out)
{
    const int bI = blockIdx.x;
    const int ct = bI & 15;
    const int s  = (bI >> 4) & (S2 - 1);
    const int b  = bI >> 7;
    const int t  = threadIdx.x;
    const int c0 = ct * CT2;

    __shared__ float sgk[CT2 * KK];
    __shared__ float scale[CT2];

    // NOTE: CT2*KK = 304 > 256 threads — MUST be a strided loop, not `if`.
    for (int idx = t; idx < CT2 * KK; idx += 256) {
        const int c = idx / KK;
        const int k = idx - c * KK;
        const float a = att[(size_t)(b * CC + c0 + c) * KK + k];
        const float sig = 1.f / (1.f + __expf(-a));
        sgk[idx] = sig * gamma[k];
    }
    __syncthreads();

    if (t < CT2) {
        float ssum = 0.f;
#define ADDK(K) ssum += sgk[t * KK + (K)];
        FOR_K(ADDK)
#undef ADDK
        scale[t] = 1.f + ssum;
    }
    __syncthreads();

    const float4* f4 = (const float4*)feature + (size_t)(b * CC + c0) * HW4;
    float4*       o4 = (float4*)out           + (size_t)(b * CC + c0) * HW4;
    const int ibase = s * CHUNK24;
#pragma unroll
    for (int c = 0; c < CT2; ++c) {
        const float sc = scale[c];
#pragma unroll
        for (int r = 0; r < CHUNK24 / 256; ++r) {   // 2 iterations
            const int i = ibase + r * 256 + t;
            const float4 f = f4[(size_t)c * HW4 + i];
            float4 o;
            o.x = f.x * sc;
            o.y = f.y * sc;
            o.z = f.z * sc;
            o.w = f.w * sc;
            o4[(size_t)c * HW4 + i] = o;
        }
    }
}

extern "C" void kernel_launch(void* const* d_in, const int* in_sizes, int n_in,
                              void* d_out, int out_size, void* d_ws, size_t ws_size,
                              hipStream_t stream) {
    const float* feature = (const float*)d_in[0];
    const float* map_    = (const float*)d_in[1];
    const float* gamma   = (const float*)d_in[2];
    float* out           = (float*)d_out;
    float* att           = (float*)d_ws;   // BB*CC*KK*4 = 155,648 B

    const size_t att_bytes  = (size_t)BB * CC * KK * sizeof(float);
    const size_t part_off   = (att_bytes + 255) & ~(size_t)255;
    const size_t part_bytes = (size_t)KK * BB * NS * CC * sizeof(float); // 19,922,944 B
    const bool   split      = ws_size >= part_off + part_bytes;
    float* part = split ? (float*)((char*)d_ws + part_off) : nullptr;

    if (!split) {
        // att is re-poisoned to 0xAA before every launch — atomic fallback
        // needs it zeroed (hipMemsetAsync on stream is graph-capture safe).
        hipMemsetAsync(att, 0, att_bytes, stream);
    }

    const int grid1 = BB * NS;                // 1024
    CGM_k1_contract<<<grid1, 256, 0, stream>>>(feature, map_, att, part);

    if (split) {
        CGM_k1b_reduce<<<BB * KK, 256, 0, stream>>>(part, att);
    }

    const int grid2 = BB * S2 * (CC / CT2);   // 1024
    CGM_k2_apply<<<grid2, 256, 0, stream>>>(feature, gamma, att, out);
}

// Round 10
// 281.807 us; speedup vs baseline: 1.2290x; 1.2290x over previous
//
#include <hip/hip_runtime.h>
#include <math.h>

#define BB 8
#define CC 256
#define KK 19
#define HW 16384
#define HW4 4096            // HW / 4 (float4 units)

#define SCH4 64             // float4 per s-chunk = 256 floats
#define NS2 (HW4 / SCH4)    // 64 s-chunks per batch

// ---- K1 history ----
// r1: LDS map broadcast + per-lane feature: 93 us (DS-heavy + spill).
// r2/r3: bigger per-thread tiles -> compiler pinned 64 VGPR -> scratch GBs.
//     Lesson: design INSIDE 64 VGPRs.
// r4/r5: map->SGPR asm; r5's per-j lgkmcnt(0) full drain = 100 us.
// r6: constant-AS map pointers (compiler-scheduled s_load_dwordx4) + staged
//     feature via global_load_lds + both-sides swizzle: best, K1 ~60-79 us,
//     total 281.
// r7: 2D wave split: DS reads halved, bank conflicts halved -> NO change
//     (82 us). DS is not the bottleneck; drains/barriers are.
// r8: per-lane direct feature: 134 us (64-line gather per instr, TA-bound).
// r9: hand-asm rotated pipeline: core dump; design also had insufficient
//     slack (one FMA-block < SMEM latency). Reverted.
// r10 (this): r6 verbatim + two safe deltas:
//   (1) j processed in PAIRS in COMPUTE: both j's 10 map quads loaded
//       before the 2x(2 ds_read + 40 FMA) group -> one SMEM drain per 2 j
//       (drains halved).
//   (2) SCH4 64 (grid 1024, 8 j-tiles/block): cold prologues halved; part
//       buffer 19.9 -> 10 MB; K1b work halved.

typedef float f32x4 __attribute__((ext_vector_type(4)));

#define AS1C(p) ((const __attribute__((address_space(1))) void*)(p))
#define AS3(p)  ((__attribute__((address_space(3))) void*)(p))

// Constant-AS vector pointer: uniform address + read-only memory -> s_load.
typedef const __attribute__((address_space(4))) f32x4* cvec4p;
#define CVEC4(p) ((cvec4p)(unsigned long long)(p))

// Per-wave uniform pointer: readfirstlane both halves (wave-uniform by
// construction; w = t>>6 is constant within a wave).
static __device__ __forceinline__ const float* uniform_ptr(const float* p) {
    unsigned long long u = (unsigned long long)p;
    unsigned lo = __builtin_amdgcn_readfirstlane((unsigned)u);
    unsigned hi = __builtin_amdgcn_readfirstlane((unsigned)(u >> 32));
    return (const float*)(((unsigned long long)hi << 32) | lo);
}

#define FMAC(AV, MV, FV)                                                 \
    AV += FV.x * MV.x; AV += FV.y * MV.y; AV += FV.z * MV.z; AV += FV.w * MV.w;

__global__ __launch_bounds__(256) void CGM_k1_contract(
    const float* __restrict__ feature,
    const float* __restrict__ map_,
    float* __restrict__ att,        // fallback target (pre-zeroed)
    float* __restrict__ part)       // [KK][BB][NS2][CC] partials, or nullptr
{
    const int bI   = blockIdx.x;            // ((b*NS2 + s) << 1) | half
    const int half = bI & 1;                // channel half: c in [half*128, +128)
    const int s    = (bI >> 1) & (NS2 - 1);
    const int b    = bI >> 7;               // NS2 == 64 -> 7 bits
    const int t    = threadIdx.x;
    const int l    = t & 63;
    const int w    = t >> 6;                // wave id 0..3 -> k-group

    // 2 x 16 KB: tile = [128 ch][8 float4], double-buffered.
    __shared__ float4 buf[2][1024];

    const int klo = w * 5;                  // 0,5,10,15
    const float* mw_raw = map_ + (size_t)b * KK * HW + (size_t)klo * HW
                        + (size_t)s * (SCH4 * 4);
    // 5th row: k=klo+4, except wave 3 re-loads k=18 (dup, never stored).
    const size_t k4off = (size_t)((w == 3) ? 3 : 4) * HW;
    const float* mw  = uniform_ptr(mw_raw);
    const float* m4b = uniform_ptr(mw_raw + k4off);

    // Constant-AS row pointers -> compiler-scheduled s_load_dwordx4.
    cvec4p cm0 = CVEC4(mw);
    cvec4p cm1 = CVEC4(mw + 1 * (size_t)HW);
    cvec4p cm2 = CVEC4(mw + 2 * (size_t)HW);
    cvec4p cm3 = CVEC4(mw + 3 * (size_t)HW);
    cvec4p cm4 = CVEC4(m4b);

    const float4* fbase = (const float4*)feature
                        + ((size_t)b * CC + half * 128) * HW4 + s * SCH4;

    // Stage tile JT into buf[BUFIDX]: linear LDS dest (wave-uniform base +
    // lane*16) + inverse-swizzled global source. 4 issues/thread, VGPR-free.
#define STAGE(BUFIDX, JT) do {                                           \
    _Pragma("unroll")                                                    \
    for (int q = 0; q < 4; ++q) {                                        \
        const int slot = q * 256 + t;                                    \
        const int chs  = slot >> 3;                                      \
        const int js   = slot & 7;                                       \
        const float4* g = fbase + (size_t)chs * HW4                      \
                        + (JT) * 8 + (js ^ (chs & 7));                   \
        __builtin_amdgcn_global_load_lds(AS1C(g),                        \
            AS3(&buf[BUFIDX][slot]), 16, 0, 0);                          \
    }                                                                    \
} while (0)

    float A00 = 0.f, A01 = 0.f, A02 = 0.f, A03 = 0.f, A04 = 0.f;  // row l
    float A10 = 0.f, A11 = 0.f, A12 = 0.f, A13 = 0.f, A14 = 0.f;  // row 64+l

    // Compute tile JT out of buf[BUFIDX], j in PAIRS: both j's 10 map quads
    // are loaded before the pair's 4 ds_reads + 80 FMAs -> the compiler
    // batches the s_loads and emits ~one lgkm drain per 2 j's (halved).
    // Swizzle (r6-validated): LDS[chs][js] = G[chs][js^(chs&7)], read
    // LDS[r][j^(r&7)] = G[r][j].
#define COMPUTE(BUFIDX, JT) do {                                         \
    const float4* bc = buf[BUFIDX];                                      \
    _Pragma("unroll")                                                    \
    for (int jp = 0; jp < 4; ++jp) {                                     \
        const int j0  = jp * 2;                                          \
        const int j1  = jp * 2 + 1;                                      \
        const int jj0 = (JT) * 8 + j0;                                   \
        const int jj1 = (JT) * 8 + j1;                                   \
        const f32x4 n00 = cm0[jj0];                                      \
        const f32x4 n01 = cm1[jj0];                                      \
        const f32x4 n02 = cm2[jj0];                                      \
        const f32x4 n03 = cm3[jj0];                                      \
        const f32x4 n04 = cm4[jj0];                                      \
        const f32x4 n10 = cm0[jj1];                                      \
        const f32x4 n11 = cm1[jj1];                                      \
        const f32x4 n12 = cm2[jj1];                                      \
        const f32x4 n13 = cm3[jj1];                                      \
        const f32x4 n14 = cm4[jj1];                                      \
        const float4 f00 = bc[(size_t)l * 8 + (j0 ^ (l & 7))];           \
        const float4 f01 = bc[(size_t)(64 + l) * 8 + (j0 ^ (l & 7))];    \
        const float4 f10 = bc[(size_t)l * 8 + (j1 ^ (l & 7))];           \
        const float4 f11 = bc[(size_t)(64 + l) * 8 + (j1 ^ (l & 7))];    \
        FMAC(A00, n00, f00) FMAC(A01, n01, f00) FMAC(A02, n02, f00)      \
        FMAC(A03, n03, f00) FMAC(A04, n04, f00)                          \
        FMAC(A10, n00, f01) FMAC(A11, n01, f01) FMAC(A12, n02, f01)      \
        FMAC(A13, n03, f01) FMAC(A14, n04, f01)                          \
        FMAC(A00, n10, f10) FMAC(A01, n11, f10) FMAC(A02, n12, f10)      \
        FMAC(A03, n13, f10) FMAC(A04, n14, f10)                          \
        FMAC(A10, n10, f11) FMAC(A11, n11, f11) FMAC(A12, n12, f11)      \
        FMAC(A13, n13, f11) FMAC(A14, n14, f11)                          \
    }                                                                    \
} while (0)

    // 2-phase pipeline over the 8 j-tiles (r6 pattern, 2x longer chain).
    STAGE(0, 0); __syncthreads();
    STAGE(1, 1); COMPUTE(0, 0); __syncthreads();
    STAGE(0, 2); COMPUTE(1, 1); __syncthreads();
    STAGE(1, 3); COMPUTE(0, 2); __syncthreads();
    STAGE(0, 4); COMPUTE(1, 3); __syncthreads();
    STAGE(1, 5); COMPUTE(0, 4); __syncthreads();
    STAGE(0, 6); COMPUTE(1, 5); __syncthreads();
    STAGE(1, 7); COMPUTE(0, 6); __syncthreads();
    COMPUTE(1, 7);

#undef STAGE
#undef COMPUTE

    const int cbase = half * 128 + l;       // + 0 / +64 for the two c-rows
    if (part) {
        // part[k][b][s][c]: per k one coalesced 256 B store per c-row.
#define STK(KI, A0v, A1v) if (klo + (KI) < KK) {                         \
        float* d = part + ((size_t)((klo + (KI)) * BB + b) * NS2 + s) * CC \
                 + cbase;                                                \
        d[0] = A0v; d[64] = A1v; }
        STK(0, A00, A10) STK(1, A01, A11) STK(2, A02, A12)
        STK(3, A03, A13) STK(4, A04, A14)
#undef STK
    } else {
        // Fallback: fp32 atomics into pre-zeroed att.
#define STK(KI, A0v, A1v) if (klo + (KI) < KK) {                         \
        atomicAdd(&att[(size_t)(b * CC + cbase)      * KK + klo + (KI)], A0v); \
        atomicAdd(&att[(size_t)(b * CC + cbase + 64) * KK + klo + (KI)], A1v); }
        STK(0, A00, A10) STK(1, A01, A11) STK(2, A02, A12)
        STK(3, A03, A13) STK(4, A04, A14)
#undef STK
    }
}

// ---- K1b: fold the NS2=64 s-chunk partials into att. ----
// part[k][b][s][c] contiguous per (b,k): 64 KB streamed with float4 loads,
// 4-way s-split across 256 threads, 4 rotating accumulators, LDS tree.
__global__ __launch_bounds__(256) void CGM_k1b_reduce(
    const float* __restrict__ part,
    float* __restrict__ att)
{
    const int bk = blockIdx.x;      // b*KK + k
    const int b  = bk / KK;
    const int k  = bk - b * KK;
    const int t  = threadIdx.x;
    const int q  = t & 63;          // float4 column: channels 4q..4q+3
    const int sg = t >> 6;          // s quarter: 16 rows

    const float4* p4 = (const float4*)(part + (size_t)(k * BB + b) * NS2 * CC)
                     + (size_t)(sg * 16) * 64 + q;

    float4 a0 = {0.f, 0.f, 0.f, 0.f}, a1 = a0, a2 = a0, a3 = a0;
#pragma unroll
    for (int i = 0; i < 16; i += 4) {
        const float4 v0 = p4[(size_t)(i + 0) * 64];
        const float4 v1 = p4[(size_t)(i + 1) * 64];
        const float4 v2 = p4[(size_t)(i + 2) * 64];
        const float4 v3 = p4[(size_t)(i + 3) * 64];
        a0.x += v0.x; a0.y += v0.y; a0.z += v0.z; a0.w += v0.w;
        a1.x += v1.x; a1.y += v1.y; a1.z += v1.z; a1.w += v1.w;
        a2.x += v2.x; a2.y += v2.y; a2.z += v2.z; a2.w += v2.w;
        a3.x += v3.x; a3.y += v3.y; a3.z += v3.z; a3.w += v3.w;
    }
    float4 r;
    r.x = (a0.x + a1.x) + (a2.x + a3.x);
    r.y = (a0.y + a1.y) + (a2.y + a3.y);
    r.z = (a0.z + a1.z) + (a2.z + a3.z);
    r.w = (a0.w + a1.w) + (a2.w + a3.w);

    __shared__ float4 red[4][64];
    red[sg][q] = r;
    __syncthreads();
    if (t < 64) {
        const float4 u0 = red[0][q], u1 = red[1][q], u2 = red[2][q], u3 = red[3][q];
        float4 o;
        o.x = (u0.x + u1.x) + (u2.x + u3.x);
        o.y = (u0.y + u1.y) + (u2.y + u3.y);
        o.z = (u0.z + u1.z) + (u2.z + u3.z);
        o.w = (u0.w + u1.w) + (u2.w + u3.w);
        float* d = att + ((size_t)b * CC + 4 * q) * KK + k;
        d[0 * KK] = o.x;
        d[1 * KK] = o.y;
        d[2 * KK] = o.z;
        d[3 * KK] = o.w;
    }
}

// ---- K2: gate + apply (frozen since round 2) ----
#define S2 8                 // hw splits
#define CT2 16               // channels per block
#define CHUNK24 (HW4 / S2)   // 512 float4

#define FOR_K(OP) OP(0) OP(1) OP(2) OP(3) OP(4) OP(5) OP(6) OP(7) OP(8) OP(9) \
                  OP(10) OP(11) OP(12) OP(13) OP(14) OP(15) OP(16) OP(17) OP(18)

__global__ __launch_bounds__(256) void CGM_k2_apply(
    const float* __restrict__ feature,
    const float* __restrict__ gamma,
    const float* __restrict__ att,
    float* __restrict__ out)
{
    const int bI = blockIdx.x;
    const int ct = bI & 15;
    const int s  = (bI >> 4) & (S2 - 1);
    const int b  = bI >> 7;
    const int t  = threadIdx.x;
    const int c0 = ct * CT2;

    __shared__ float sgk[CT2 * KK];
    __shared__ float scale[CT2];

    // NOTE: CT2*KK = 304 > 256 threads — MUST be a strided loop, not `if`.
    for (int idx = t; idx < CT2 * KK; idx += 256) {
        const int c = idx / KK;
        const int k = idx - c * KK;
        const float a = att[(size_t)(b * CC + c0 + c) * KK + k];
        const float sig = 1.f / (1.f + __expf(-a));
        sgk[idx] = sig * gamma[k];
    }
    __syncthreads();

    if (t < CT2) {
        float ssum = 0.f;
#define ADDK(K) ssum += sgk[t * KK + (K)];
        FOR_K(ADDK)
#undef ADDK
        scale[t] = 1.f + ssum;
    }
    __syncthreads();

    const float4* f4 = (const float4*)feature + (size_t)(b * CC + c0) * HW4;
    float4*       o4 = (float4*)out           + (size_t)(b * CC + c0) * HW4;
    const int ibase = s * CHUNK24;
#pragma unroll
    for (int c = 0; c < CT2; ++c) {
        const float sc = scale[c];
#pragma unroll
        for (int r = 0; r < CHUNK24 / 256; ++r) {   // 2 iterations
            const int i = ibase + r * 256 + t;
            const float4 f = f4[(size_t)c * HW4 + i];
            float4 o;
            o.x = f.x * sc;
            o.y = f.y * sc;
            o.z = f.z * sc;
            o.w = f.w * sc;
            o4[(size_t)c * HW4 + i] = o;
        }
    }
}

extern "C" void kernel_launch(void* const* d_in, const int* in_sizes, int n_in,
                              void* d_out, int out_size, void* d_ws, size_t ws_size,
                              hipStream_t stream) {
    const float* feature = (const float*)d_in[0];
    const float* map_    = (const float*)d_in[1];
    const float* gamma   = (const float*)d_in[2];
    float* out           = (float*)d_out;
    float* att           = (float*)d_ws;   // BB*CC*KK*4 = 155,648 B

    const size_t att_bytes  = (size_t)BB * CC * KK * sizeof(float);
    const size_t part_off   = (att_bytes + 255) & ~(size_t)255;
    const size_t part_bytes = (size_t)KK * BB * NS2 * CC * sizeof(float); // 9,961,472 B
    const bool   split      = ws_size >= part_off + part_bytes;
    float* part = split ? (float*)((char*)d_ws + part_off) : nullptr;

    if (!split) {
        // att is re-poisoned to 0xAA before every launch — atomic fallback
        // needs it zeroed (hipMemsetAsync on stream is graph-capture safe).
        hipMemsetAsync(att, 0, att_bytes, stream);
    }

    const int grid1 = BB * NS2 * 2;           // 1024 (channel halves)
    CGM_k1_contract<<<grid1, 256, 0, stream>>>(feature, map_, att, part);

    if (split) {
        CGM_k1b_reduce<<<BB * KK, 256, 0, stream>>>(part, att);
    }

    const int grid2 = BB * S2 * (CC / CT2);   // 1024
    CGM_k2_apply<<<grid2, 256, 0, stream>>>(feature, gamma, att, out);
}